// Round 8
// baseline (12.423 us; speedup 1.0000x reference)
//
#include <hip/hip_runtime.h>

#define NUM_PAGES 1048576
#define TPP 32
#define SLOTS 256
#define MPPS 4096
#define NBLK 1024
#define NTHR 256
#define NR4 (NUM_PAGES / 1024)   // 4096 scan rounds of 256 pages (64 int4) each

// block b copies int4 gi = b*256+t of ps and pm.
// scan round r covers pages [r*256, r*256+256): round 4b+w, lane l == pages of
// copy int4 of thread t=w*64+l in block b -> in-register ps patches.

__global__ __launch_bounds__(NTHR) void fused(
    const int* __restrict__ ps, const int* __restrict__ pm,
    const int* __restrict__ seq, const int* __restrict__ npu,
    const int* __restrict__ cp, int* __restrict__ out)
{
    const int t = threadIdx.x, b = blockIdx.x;
    const int lane = t & 63, wave = t >> 6;

    int* out_ps  = out;                     // NUM_PAGES
    int* out_pm  = out + NUM_PAGES;         // SLOTS*MPPS == NUM_PAGES
    int* out_seq = out + 2 * NUM_PAGES;
    int* out_npu = out_seq + SLOTS;
    int* out_cp  = out_npu + SLOTS;
    int* out_cpp = out_cp + SLOTS;

    __shared__ int s_free[SLOTS];   // block 0 only: rank -> page
    __shared__ int s_rank[SLOTS];   // block 0 only: slot -> rank or -1
    __shared__ int s_cpo[SLOTS];    // block 0 only: original current_page

    const int4* ps4 = reinterpret_cast<const int4*>(ps);
    const int gi = b * NTHR + t;
    const int my_round = 4 * b + wave;

    // ---- issue all loads up front ------------------------------------------
    const int4 sq4 = reinterpret_cast<const int4*>(seq)[lane];
    const int4 cq4 = reinterpret_cast<const int4*>(cp)[lane];
    const int4 nu4 = reinterpret_cast<const int4*>(npu)[lane];
    int4 A = ps4[lane];                     // scan rounds 0..2 prefetch
    int4 B = ps4[64 + lane];
    int4 C = ps4[128 + lane];
    const int4 pv = ps4[gi];                // my copy elements
    const int4 mv = reinterpret_cast<const int4*>(pm)[gi];

    // ---- slot math, 4 slots/lane (slot = 4*lane+j), redundant per wave -----
    int ns0 = sq4.x + (cq4.x != -1), nn0 = (ns0 + TPP - 1) >> 5;
    int ns1 = sq4.y + (cq4.y != -1), nn1 = (ns1 + TPP - 1) >> 5;
    int ns2 = sq4.z + (cq4.z != -1), nn2 = (ns2 + TPP - 1) >> 5;
    int ns3 = sq4.w + (cq4.w != -1), nn3 = (ns3 + TPP - 1) >> 5;
    int nb = (nn0 > nu4.x ? 1 : 0) | (nn1 > nu4.y ? 2 : 0) |
             (nn2 > nu4.z ? 4 : 0) | (nn3 > nu4.w ? 8 : 0);

    int cnt = __popc(nb), x = cnt;
    #pragma unroll
    for (int o = 1; o < 64; o <<= 1) { int y = __shfl_up(x, o); if (lane >= o) x += y; }
    const int K = __shfl(x, 63);
    const int base_r = x - cnt;
    const int iv0 = (nb & 1) ? base_r : -1;
    const int iv1 = (nb & 2) ? base_r + (nb & 1) : -1;
    const int iv2 = (nb & 4) ? base_r + __popc(nb & 3) : -1;
    const int iv3 = (nb & 8) ? base_r + __popc(nb & 7) : -1;

    if (b == 0 && wave == 0) {              // slot vectors + block-0 LDS meta
        int4 o;
        o.x = ns0; o.y = ns1; o.z = ns2; o.w = ns3;
        reinterpret_cast<int4*>(out_seq)[lane] = o;
        o.x = nn0; o.y = nn1; o.z = nn2; o.w = nn3;
        reinterpret_cast<int4*>(out_npu)[lane] = o;
        o.x = ns0 ? ((ns0 - 1) & 31) : 0;
        o.y = ns1 ? ((ns1 - 1) & 31) : 0;
        o.z = ns2 ? ((ns2 - 1) & 31) : 0;
        o.w = ns3 ? ((ns3 - 1) & 31) : 0;
        reinterpret_cast<int4*>(out_cpp)[lane] = o;
        o.x = iv0; o.y = iv1; o.z = iv2; o.w = iv3;
        reinterpret_cast<int4*>(s_rank)[lane] = o;
        reinterpret_cast<int4*>(s_cpo)[lane] = cq4;
    }

    // my block's pm-patch target: slot b>>2, column npu[b>>2], rank of that slot
    const int slot_b = b >> 2;
    const int src_lane = slot_b >> 2;
    const int jb = slot_b & 3;              // uniform
    int my_iv = (jb == 0) ? iv0 : (jb == 1) ? iv1 : (jb == 2) ? iv2 : iv3;
    int my_nu = (jb == 0) ? nu4.x : (jb == 1) ? nu4.y : (jb == 2) ? nu4.z : nu4.w;
    const int tr    = __shfl(my_iv, src_lane);  // target alloc rank, -1 = none
    const int col_b = __shfl(my_nu, src_lane);  // pm column to patch

    // ---- barrier-free scan: every wave redundantly, registers only ---------
    int sf = 0, pmask = 0, nfp_pm = -1, r = 0;
    while (sf < K && r < NR4) {
        int4 v = A; A = B; B = C;
        C = (r + 3 < NR4) ? ps4[(r + 3) * 64 + lane] : make_int4(1, 1, 1, 1);
        int m = ((v.x == 0) ? 1 : 0) | ((v.y == 0) ? 2 : 0) |
                ((v.z == 0) ? 4 : 0) | ((v.w == 0) ? 8 : 0);
        if (r == 0 && lane == 0) m &= ~1;   // page 0 never allocatable
        int q = __popc(m), xx = q;
        #pragma unroll
        for (int o = 1; o < 64; o <<= 1) { int y = __shfl_up(xx, o); if (lane >= o) xx += y; }
        int pos = sf + xx - q;              // global rank of my first free
        int p0 = pos;
        int p1 = pos + (m & 1);
        int p2 = pos + __popc(m & 3);
        int p3 = pos + __popc(m & 7);
        int pg = r * 256 + lane * 4;
        if (r == my_round) {                // wave-uniform: my own copy pages
            if ((m & 1) && p0 < K) pmask |= 1;
            if ((m & 2) && p1 < K) pmask |= 2;
            if ((m & 4) && p2 < K) pmask |= 4;
            if ((m & 8) && p3 < K) pmask |= 8;
        }
        if (b == 0) {                       // rank -> page table for cp gather
            if ((m & 1) && p0 < K) s_free[p0] = pg;
            if ((m & 2) && p1 < K) s_free[p1] = pg + 1;
            if ((m & 4) && p2 < K) s_free[p2] = pg + 2;
            if ((m & 8) && p3 < K) s_free[p3] = pg + 3;
        }
        if (tr >= 0 && nfp_pm < 0) {        // find my slot's page (uniform cond)
            int fl = -1;
            if ((m & 1) && p0 == tr) fl = pg;
            if ((m & 2) && p1 == tr) fl = pg + 1;
            if ((m & 4) && p2 == tr) fl = pg + 2;
            if ((m & 8) && p3 == tr) fl = pg + 3;
            unsigned long long bb = __ballot(fl >= 0);
            if (bb) nfp_pm = __shfl(fl, __ffsll(bb) - 1);
        }
        sf += __shfl(xx, 63);
        ++r;
    }
    const int fe = (sf < K) ? sf : K;       // frees actually found

    // ---- patch my registers, then single fused store -----------------------
    int4 opv = pv, omv = mv;
    if (gi == 0 && fe < K) pmask |= 1;      // exhausted pool: ref sets ps[0]=1
    if (pmask & 1) opv.x = 1;
    if (pmask & 2) opv.y = 1;
    if (pmask & 4) opv.z = 1;
    if (pmask & 8) opv.w = 1;
    if (tr >= 0) {                          // pm patch if my int4 covers (slot_b, col_b)
        int nfp = (tr < fe) ? nfp_pm : 0;
        int d = col_b - ((b & 3) << 10) - (t << 2);
        if (d == 0) omv.x = nfp;
        else if (d == 1) omv.y = nfp;
        else if (d == 2) omv.z = nfp;
        else if (d == 3) omv.w = nfp;
    }
    reinterpret_cast<int4*>(out_ps)[gi] = opv;
    reinterpret_cast<int4*>(out_pm)[gi] = omv;

    // ---- block 0 only: cp vector via LDS gather ----------------------------
    if (b == 0) {
        __syncthreads();
        int rk = s_rank[t];
        out_cp[t] = (rk >= 0) ? ((rk < fe) ? s_free[rk] : 0) : s_cpo[t];
    }
}

// ---------------------------------------------------------------------------
extern "C" void kernel_launch(void* const* d_in, const int* in_sizes, int n_in,
                              void* d_out, int out_size, void* d_ws, size_t ws_size,
                              hipStream_t stream)
{
    const int* page_status = (const int*)d_in[0];
    const int* page_map    = (const int*)d_in[1];
    const int* seq         = (const int*)d_in[2];
    const int* npu         = (const int*)d_in[3];
    const int* cp          = (const int*)d_in[4];
    // d_in[5] (current_page_position) unused by the reference update.

    fused<<<NBLK, NTHR, 0, stream>>>(
        page_status, page_map, seq, npu, cp, (int*)d_out);
}

// Round 9
// 10.472 us; speedup vs baseline: 1.1863x; 1.1863x over previous
//
#include <hip/hip_runtime.h>

#define NUM_PAGES 1048576
#define TPP 32
#define SLOTS 256
#define MPPS 4096
#define NBLK 1024
#define NTHR 256
// block b copies int4 gi = b*256+t of ps and pm (pages [b*1024, b*1024+1024)).
// Wide scan round: thread t holds pages {t*4..+4} of chunks 0,1,2 (0..3071).

__global__ __launch_bounds__(NTHR) void fused(
    const int* __restrict__ ps, const int* __restrict__ pm,
    const int* __restrict__ seq, const int* __restrict__ npu,
    const int* __restrict__ cp, int* __restrict__ out)
{
    const int t = threadIdx.x, b = blockIdx.x;
    const int lane = t & 63, wave = t >> 6;

    int* out_ps  = out;                     // NUM_PAGES
    int* out_pm  = out + NUM_PAGES;         // SLOTS*MPPS == NUM_PAGES
    int* out_seq = out + 2 * NUM_PAGES;
    int* out_npu = out_seq + SLOTS;
    int* out_cp  = out_npu + SLOTS;
    int* out_cpp = out_cp + SLOTS;

    __shared__ int s_w[12];         // 4 waves x 3 chunks partial sums
    __shared__ int s_free[SLOTS];   // block 0 only: rank -> page
    __shared__ int s_rank[SLOTS];   // block 0 only: slot -> rank or -1
    __shared__ int s_cpo[SLOTS];    // block 0 only: original current_page
    __shared__ int s_pmval;         // page id of this block's pm-patch rank

    const int4* ps4 = reinterpret_cast<const int4*>(ps);
    const int gi = b * NTHR + t;

    // ---- issue all loads up front ------------------------------------------
    const int4 sq4 = reinterpret_cast<const int4*>(seq)[lane];
    const int4 cq4 = reinterpret_cast<const int4*>(cp)[lane];
    const int4 nu4 = reinterpret_cast<const int4*>(npu)[lane];
    const int4 pc0 = ps4[t];                // pages 0..1023
    const int4 pc1 = ps4[NTHR + t];         // pages 1024..2047
    const int4 pc2 = ps4[2 * NTHR + t];     // pages 2048..3071
    int4 pv = ps4[gi];                      // my copy elements
    int4 mv = reinterpret_cast<const int4*>(pm)[gi];

    if (t == 0) s_pmval = 0;                // default (used only when tr>=fe)

    // ---- slot math, 4 slots/lane, redundant per wave (shfl-only) -----------
    int ns0 = sq4.x + (cq4.x != -1), nn0 = (ns0 + TPP - 1) >> 5;
    int ns1 = sq4.y + (cq4.y != -1), nn1 = (ns1 + TPP - 1) >> 5;
    int ns2 = sq4.z + (cq4.z != -1), nn2 = (ns2 + TPP - 1) >> 5;
    int ns3 = sq4.w + (cq4.w != -1), nn3 = (ns3 + TPP - 1) >> 5;
    int nb = (nn0 > nu4.x ? 1 : 0) | (nn1 > nu4.y ? 2 : 0) |
             (nn2 > nu4.z ? 4 : 0) | (nn3 > nu4.w ? 8 : 0);
    int cnt = __popc(nb), x = cnt;
    #pragma unroll
    for (int o = 1; o < 64; o <<= 1) { int y = __shfl_up(x, o); if (lane >= o) x += y; }
    const int K = __shfl(x, 63);
    const int base_r = x - cnt;
    const int iv0 = (nb & 1) ? base_r : -1;
    const int iv1 = (nb & 2) ? base_r + (nb & 1) : -1;
    const int iv2 = (nb & 4) ? base_r + __popc(nb & 3) : -1;
    const int iv3 = (nb & 8) ? base_r + __popc(nb & 7) : -1;

    if (b == 0 && wave == 0) {              // slot vectors + block-0 tables
        int4 o;
        o.x = ns0; o.y = ns1; o.z = ns2; o.w = ns3;
        reinterpret_cast<int4*>(out_seq)[lane] = o;
        o.x = nn0; o.y = nn1; o.z = nn2; o.w = nn3;
        reinterpret_cast<int4*>(out_npu)[lane] = o;
        o.x = ns0 ? ((ns0 - 1) & 31) : 0;
        o.y = ns1 ? ((ns1 - 1) & 31) : 0;
        o.z = ns2 ? ((ns2 - 1) & 31) : 0;
        o.w = ns3 ? ((ns3 - 1) & 31) : 0;
        reinterpret_cast<int4*>(out_cpp)[lane] = o;
        o.x = iv0; o.y = iv1; o.z = iv2; o.w = iv3;
        reinterpret_cast<int4*>(s_rank)[lane] = o;
        reinterpret_cast<int4*>(s_cpo)[lane] = cq4;
    }

    // my block's pm-patch target: slot b>>2, column npu[slot], that slot's rank
    const int slot_b = b >> 2;
    const int jb = slot_b & 3;
    int my_iv = (jb == 0) ? iv0 : (jb == 1) ? iv1 : (jb == 2) ? iv2 : iv3;
    int my_nu = (jb == 0) ? nu4.x : (jb == 1) ? nu4.y : (jb == 2) ? nu4.z : nu4.w;
    const int tr    = __shfl(my_iv, slot_b >> 2);   // alloc rank, -1 = none
    const int col_b = __shfl(my_nu, slot_b >> 2);   // pm column to patch

    // ---- wide scan: pages 0..3071, one round, 3 interleaved shfl chains ----
    auto fm = [](int4 v) {
        return ((v.x == 0) ? 1 : 0) | ((v.y == 0) ? 2 : 0) |
               ((v.z == 0) ? 4 : 0) | ((v.w == 0) ? 8 : 0);
    };
    int m0 = fm(pc0), m1 = fm(pc1), m2 = fm(pc2);
    if (t == 0) m0 &= ~1;                   // page 0 never allocatable
    int q0 = __popc(m0), q1 = __popc(m1), q2 = __popc(m2);
    int x0 = q0, x1 = q1, x2 = q2;
    #pragma unroll
    for (int o = 1; o < 64; o <<= 1) {
        int y0 = __shfl_up(x0, o), y1 = __shfl_up(x1, o), y2 = __shfl_up(x2, o);
        if (lane >= o) { x0 += y0; x1 += y1; x2 += y2; }
    }
    if (lane == 63) { s_w[wave] = x0; s_w[4 + wave] = x1; s_w[8 + wave] = x2; }
    __syncthreads();                        // barrier 1
    int w0 = 0, w1 = 0, w2 = 0, T0 = 0, T1 = 0, T2 = 0;
    #pragma unroll
    for (int w = 0; w < 4; ++w) {
        int a0 = s_w[w], a1 = s_w[4 + w], a2 = s_w[8 + w];
        if (w < wave) { w0 += a0; w1 += a1; w2 += a2; }
        T0 += a0; T1 += a1; T2 += a2;
    }
    const int pos0 = w0 + x0 - q0;                   // excl. rank, chunk 0
    const int pos1 = T0 + w1 + x1 - q1;              // chunk 1
    const int pos2 = T0 + T1 + w2 + x2 - q2;         // chunk 2
    const int fe_fast = T0 + T1 + T2;

    // block 0: rank -> page table; any block: search my pm-target rank
    if (b == 0) {
        #pragma unroll
        for (int j = 0; j < 4; ++j) {
            if (m0 & (1 << j)) { int p = pos0 + __popc(m0 & ((1 << j) - 1)); if (p < K) s_free[p] = t * 4 + j; }
            if (m1 & (1 << j)) { int p = pos1 + __popc(m1 & ((1 << j) - 1)); if (p < K) s_free[p] = 1024 + t * 4 + j; }
            if (m2 & (1 << j)) { int p = pos2 + __popc(m2 & ((1 << j) - 1)); if (p < K) s_free[p] = 2048 + t * 4 + j; }
        }
    }
    if (tr >= 0) {
        int fl = -1;
        #pragma unroll
        for (int j = 0; j < 4; ++j) {
            if (m0 & (1 << j)) { if (pos0 + __popc(m0 & ((1 << j) - 1)) == tr) fl = t * 4 + j; }
            if (m1 & (1 << j)) { if (pos1 + __popc(m1 & ((1 << j) - 1)) == tr) fl = 1024 + t * 4 + j; }
            if (m2 & (1 << j)) { if (pos2 + __popc(m2 & ((1 << j) - 1)) == tr) fl = 2048 + t * 4 + j; }
        }
        if (fl >= 0) s_pmval = fl;
    }

    // fast-path in-register ps patches (blocks 0-2 own pages 0..3071)
    int pmask = 0;
    if (b < 3) {
        int mm = (b == 0) ? m0 : (b == 1) ? m1 : m2;
        int pp = (b == 0) ? pos0 : (b == 1) ? pos1 : pos2;
        #pragma unroll
        for (int j = 0; j < 4; ++j)
            if (mm & (1 << j)) { int p = pp + __popc(mm & ((1 << j) - 1)); if (p < K) pmask |= 1 << j; }
    }

    // ---- generic fallback: frees beyond page 3071 (cold, never hit here) ---
    int fe_total = fe_fast;
    for (int ch = 3; (ch << 10) < NUM_PAGES && fe_total < K; ++ch) {
        int4 v = ps4[(ch << 8) + t];
        int m = fm(v);
        int q = __popc(m), xx = q;
        #pragma unroll
        for (int o = 1; o < 64; o <<= 1) { int y = __shfl_up(xx, o); if (lane >= o) xx += y; }
        if (lane == 63) s_w[wave] = xx;
        __syncthreads();
        int wo = 0, T = 0;
        #pragma unroll
        for (int w = 0; w < 4; ++w) { if (w < wave) wo += s_w[w]; T += s_w[w]; }
        int pos = fe_total + wo + xx - q;
        #pragma unroll
        for (int j = 0; j < 4; ++j) if (m & (1 << j)) {
            int p = pos + __popc(m & ((1 << j) - 1));
            if (p < K) {
                int pg = (ch << 10) + (t << 2) + j;
                if (b == 0) s_free[p] = pg;
                if (p == tr) s_pmval = pg;
                if (b == ch) pmask |= 1 << j;   // scan thread t == copy thread t
            }
        }
        fe_total += T;
        __syncthreads();
    }
    const int fe = (fe_total < K) ? fe_total : K;
    if (K > fe_total && gi == 0) pmask |= 1;     // exhausted pool: ps[0]=1

    __syncthreads();                        // barrier 2: s_pmval/s_free ready

    // ---- apply in-register patches, single fused store ---------------------
    if (pmask & 1) pv.x = 1;
    if (pmask & 2) pv.y = 1;
    if (pmask & 4) pv.z = 1;
    if (pmask & 8) pv.w = 1;
    if (tr >= 0) {                          // pm patch if my int4 covers (slot_b, col_b)
        int nfp = (tr < fe) ? s_pmval : 0;
        int d = col_b - ((b & 3) << 10) - (t << 2);
        if (d == 0) mv.x = nfp;
        else if (d == 1) mv.y = nfp;
        else if (d == 2) mv.z = nfp;
        else if (d == 3) mv.w = nfp;
    }
    reinterpret_cast<int4*>(out_ps)[gi] = pv;
    reinterpret_cast<int4*>(out_pm)[gi] = mv;

    if (b == 0) {                           // cp vector via block-0 tables
        int rk = s_rank[t];
        out_cp[t] = (rk >= 0) ? ((rk < fe) ? s_free[rk] : 0) : s_cpo[t];
    }
}

// ---------------------------------------------------------------------------
extern "C" void kernel_launch(void* const* d_in, const int* in_sizes, int n_in,
                              void* d_out, int out_size, void* d_ws, size_t ws_size,
                              hipStream_t stream)
{
    const int* page_status = (const int*)d_in[0];
    const int* page_map    = (const int*)d_in[1];
    const int* seq         = (const int*)d_in[2];
    const int* npu         = (const int*)d_in[3];
    const int* cp          = (const int*)d_in[4];
    // d_in[5] (current_page_position) unused by the reference update.

    fused<<<NBLK, NTHR, 0, stream>>>(
        page_status, page_map, seq, npu, cp, (int*)d_out);
}